// Round 1
// baseline (312.948 us; speedup 1.0000x reference)
//
#include <hip/hip_runtime.h>
#include <hip/hip_bf16.h>

#define NLAB  24
#define LDIM  256
#define LSEQ  512
#define DDIM  1024
#define NOUT  12288            /* NLAB*LDIM*2 */
#define NEGV  (-10000.0f)
#define MOFF  50331648L        /* 8*24*512*512 */

typedef __attribute__((ext_vector_type(8))) short short8;
typedef __attribute__((ext_vector_type(4))) float f32x4;
typedef unsigned short u16;
typedef unsigned int   u32;

typedef const __attribute__((address_space(1))) void gvoid_t;
typedef __attribute__((address_space(3))) void lvoid_t;

__device__ __forceinline__ u16 f2bf(float f) {
  u32 u = __builtin_bit_cast(u32, f);
  u32 r = u + 0x7FFFu + ((u >> 16) & 1u);
  return (u16)(r >> 16);
}

__device__ __forceinline__ void g2l16(const u16* g, u16* l) {
  __builtin_amdgcn_global_load_lds((gvoid_t*)g, (lvoid_t*)l, 16, 0, 0);
}

/* ---------------- fp32 -> bf16 conversion of features and w_ff ------------- */
__global__ void cvt_bf16_kernel(const float* __restrict__ feat,
                                const float* __restrict__ wff,
                                u16* __restrict__ fA, u16* __restrict__ fB) {
  const long NA = 4194304L;      /* 4096*1024 */
  const long NB = 12582912L;     /* 12288*1024 */
  const long NQ = (NA + NB) / 4;
  long stride = (long)gridDim.x * blockDim.x;
  for (long i = (long)blockIdx.x * blockDim.x + threadIdx.x; i < NQ; i += stride) {
    long e = i * 4;
    const float* s; u16* d;
    if (e < NA) { s = feat + e;        d = fA + e; }
    else        { s = wff + (e - NA);  d = fB + (e - NA); }
    float4 v = *reinterpret_cast<const float4*>(s);
    ushort4 o;
    o.x = f2bf(v.x); o.y = f2bf(v.y); o.z = f2bf(v.z); o.w = f2bf(v.w);
    *reinterpret_cast<ushort4*>(d) = o;
  }
}

/* ---------------- FF GEMM: x = relu(A * B^T + b), de-interleave ------------ */
/* A: [4096,1024] bf16, B: [12288,1024] bf16 (w_ff is already [N,K] row-major) */
__global__ __launch_bounds__(256)
void ff_gemm_kernel(const u16* __restrict__ A, const u16* __restrict__ B,
                    const float* __restrict__ bff,
                    u16* __restrict__ sf, u16* __restrict__ ef) {
  __shared__ __align__(16) u16 As[128 * 32];
  __shared__ __align__(16) u16 Bs[128 * 32];
  const int tid  = threadIdx.x;
  const int lane = tid & 63;
  const int wv   = tid >> 6;
  const int wm   = wv >> 1, wn = wv & 1;
  const int tm = blockIdx.x / (NOUT / 128);
  const int tn = blockIdx.x % (NOUT / 128);
  const int rowA0 = tm * 128, rowB0 = tn * 128;

  const int srow = tid >> 2;
  const int scol = (tid & 3) * 8;
  const u16* ga = A + (long)(rowA0 + srow) * DDIM + scol;
  const u16* gb = B + (long)(rowB0 + srow) * DDIM + scol;
  u16* la = As + tid * 8;
  u16* lb = Bs + tid * 8;

  f32x4 acc[4][4] = {};
  const int lr = lane & 15;
  const int lk = (lane >> 4) * 8;

  for (int k0 = 0; k0 < DDIM; k0 += 32) {
    g2l16(ga + k0,             la);
    g2l16(ga + k0 + 64 * DDIM, la + 2048);
    g2l16(gb + k0,             lb);
    g2l16(gb + k0 + 64 * DDIM, lb + 2048);
    __syncthreads();
    short8 af[4], bfr[4];
#pragma unroll
    for (int f = 0; f < 4; ++f) {
      af[f]  = *reinterpret_cast<const short8*>(As + (wm * 64 + f * 16 + lr) * 32 + lk);
      bfr[f] = *reinterpret_cast<const short8*>(Bs + (wn * 64 + f * 16 + lr) * 32 + lk);
    }
#pragma unroll
    for (int i = 0; i < 4; ++i)
#pragma unroll
      for (int j = 0; j < 4; ++j)
        acc[i][j] = __builtin_amdgcn_mfma_f32_16x16x32_bf16(af[i], bfr[j], acc[i][j], 0, 0, 0);
    __syncthreads();
  }

  /* epilogue: +bias, relu, bf16, scatter into sf/ef [b][label][l][d] */
  const int r0 = (lane >> 4) * 4;
#pragma unroll
  for (int j = 0; j < 4; ++j) {
    const int o = rowB0 + wn * 64 + j * 16 + lr;
    const float bv = bff[o];
    const int label = o >> 9, d = (o >> 1) & 255, se = o & 1;
    u16* dst0 = se ? ef : sf;
#pragma unroll
    for (int i = 0; i < 4; ++i) {
#pragma unroll
      for (int r = 0; r < 4; ++r) {
        const int m = rowA0 + wm * 64 + i * 16 + r0 + r;
        const int b = m >> 9, ll = m & 511;
        float v = acc[i][j][r] + bv;
        v = v > 0.f ? v : 0.f;
        dst0[((long)(b * NLAB + label) * LSEQ + ll) * LDIM + d] = f2bf(v);
      }
    }
  }
}

/* ------------- Biaffine: per (b,label) S = sf * ef^T, dual write ----------- */
__global__ __launch_bounds__(256)
void biaffine_kernel(const u16* __restrict__ sf, const u16* __restrict__ ef,
                     const float* __restrict__ bias, const int* __restrict__ mask,
                     float* __restrict__ out) {
  __shared__ __align__(16) u16 As[128 * 32];
  __shared__ __align__(16) u16 Bs[128 * 32];
  const int tid = threadIdx.x, lane = tid & 63, wv = tid >> 6;
  const int wm = wv >> 1, wn = wv & 1;
  const int bl   = blockIdx.x >> 4;      /* b*NLAB + label */
  const int tile = blockIdx.x & 15;
  const int tm = tile >> 2, tn = tile & 3;
  const int b = bl / NLAB, label = bl - b * NLAB;
  const u16* Abase = sf + (long)bl * LSEQ * LDIM;
  const u16* Bbase = ef + (long)bl * LSEQ * LDIM;
  const int rowA0 = tm * 128, rowB0 = tn * 128;

  const int srow = tid >> 2, scol = (tid & 3) * 8;
  const u16* ga = Abase + (long)(rowA0 + srow) * LDIM + scol;
  const u16* gb = Bbase + (long)(rowB0 + srow) * LDIM + scol;
  u16* la = As + tid * 8;
  u16* lb = Bs + tid * 8;

  f32x4 acc[4][4] = {};
  const int lr = lane & 15, lk = (lane >> 4) * 8;

  for (int k0 = 0; k0 < LDIM; k0 += 32) {
    g2l16(ga + k0,             la);
    g2l16(ga + k0 + 64 * LDIM, la + 2048);
    g2l16(gb + k0,             lb);
    g2l16(gb + k0 + 64 * LDIM, lb + 2048);
    __syncthreads();
    short8 af[4], bfr[4];
#pragma unroll
    for (int f = 0; f < 4; ++f) {
      af[f]  = *reinterpret_cast<const short8*>(As + (wm * 64 + f * 16 + lr) * 32 + lk);
      bfr[f] = *reinterpret_cast<const short8*>(Bs + (wn * 64 + f * 16 + lr) * 32 + lk);
    }
#pragma unroll
    for (int i = 0; i < 4; ++i)
#pragma unroll
      for (int j = 0; j < 4; ++j)
        acc[i][j] = __builtin_amdgcn_mfma_f32_16x16x32_bf16(af[i], bfr[j], acc[i][j], 0, 0, 0);
    __syncthreads();
  }

  const float bv = bias[label];
  const int r0 = (lane >> 4) * 4;
  const long obase0 = (long)bl * LSEQ * LSEQ;
#pragma unroll
  for (int i = 0; i < 4; ++i) {
#pragma unroll
    for (int r = 0; r < 4; ++r) {
      const int s = rowA0 + wm * 64 + i * 16 + r0 + r;
      const bool ms = (mask[b * LSEQ + s] != 0);
#pragma unroll
      for (int j = 0; j < 4; ++j) {
        const int e = rowB0 + wn * 64 + j * 16 + lr;
        float v = acc[i][j][r] + bv;
        u32 bits = __builtin_bit_cast(u32, v);
        if ((bits & 0x7F800000u) == 0x7F800000u) v = NEGV;  /* inf or nan */
        const long idx = obase0 + (long)s * LSEQ + e;
        out[idx] = v;
        const bool keep = (s <= e) && ms && (mask[b * LSEQ + e] != 0);
        out[MOFF + idx] = keep ? v : NEGV;
      }
    }
  }
}

extern "C" void kernel_launch(void* const* d_in, const int* in_sizes, int n_in,
                              void* d_out, int out_size, void* d_ws, size_t ws_size,
                              hipStream_t stream) {
  const float* feat = (const float*)d_in[0];
  const int*   mask = (const int*)d_in[1];
  const float* wff  = (const float*)d_in[2];
  const float* bff  = (const float*)d_in[3];
  const float* bias = (const float*)d_in[4];
  float* out = (float*)d_out;

  u16* fA = (u16*)d_ws;                 /*  4,194,304 elems =  8 MiB  */
  u16* fB = fA + 4194304L;              /* 12,582,912 elems = 24 MiB  */
  u16* sf = fB + 12582912L;             /* 25,165,824 elems = 48 MiB  */
  u16* ef = sf + 25165824L;             /* 25,165,824 elems = 48 MiB  */

  cvt_bf16_kernel<<<2048, 256, 0, stream>>>(feat, wff, fA, fB);
  ff_gemm_kernel<<<dim3(32 * (NOUT / 128)), 256, 0, stream>>>(fA, fB, bff, sf, ef);
  biaffine_kernel<<<dim3(192 * 16), 256, 0, stream>>>(sf, ef, bias, mask, out);
}

// Round 2
// 254.032 us; speedup vs baseline: 1.2319x; 1.2319x over previous
//
#include <hip/hip_runtime.h>
#include <hip/hip_bf16.h>

#define NLAB  24
#define LDIM  256
#define LSEQ  512
#define DDIM  1024
#define NOUT  12288            /* NLAB*LDIM*2 */
#define NEGV  (-10000.0f)
#define MOFF  50331648L        /* 192*512*512 */

typedef __attribute__((ext_vector_type(8))) short short8;
typedef __attribute__((ext_vector_type(4))) float f32x4;
typedef unsigned short u16;
typedef unsigned int   u32;

typedef const __attribute__((address_space(1))) void gvoid_t;
typedef __attribute__((address_space(3))) void lvoid_t;

__device__ __forceinline__ u16 f2bf(float f) {
  u32 u = __builtin_bit_cast(u32, f);
  u32 r = u + 0x7FFFu + ((u >> 16) & 1u);
  return (u16)(r >> 16);
}

__device__ __forceinline__ void g2l16(const u16* g, u16* l) {
  __builtin_amdgcn_global_load_lds((gvoid_t*)g, (lvoid_t*)l, 16, 0, 0);
}

/* ---------------- fp32 -> bf16 conversion of features and w_ff ------------- */
__global__ void cvt_bf16_kernel(const float* __restrict__ feat,
                                const float* __restrict__ wff,
                                u16* __restrict__ fA, u16* __restrict__ fB) {
  const long NA = 4194304L;      /* 4096*1024 */
  const long NB = 12582912L;     /* 12288*1024 */
  const long NQ = (NA + NB) / 4;
  long stride = (long)gridDim.x * blockDim.x;
  for (long i = (long)blockIdx.x * blockDim.x + threadIdx.x; i < NQ; i += stride) {
    long e = i * 4;
    const float* s; u16* d;
    if (e < NA) { s = feat + e;        d = fA + e; }
    else        { s = wff + (e - NA);  d = fB + (e - NA); }
    float4 v = *reinterpret_cast<const float4*>(s);
    ushort4 o;
    o.x = f2bf(v.x); o.y = f2bf(v.y); o.z = f2bf(v.z); o.w = f2bf(v.w);
    *reinterpret_cast<ushort4*>(d) = o;
  }
}

/* Stage one 256x64 bf16 K-tile into LDS (linear dest, inverse-swizzled src).
   PERM: apply the epilogue column permutation to the global row index (B of ff). */
template<int LDK, bool PERM>
__device__ __forceinline__ void stage_tile(const u16* __restrict__ gbase, int row0,
                                           int k0, u16* lbuf, int t) {
#pragma unroll
  for (int l = 0; l < 4; ++l) {
    const int rt = l * 64 + (t >> 3);                 /* tile row 0..255 */
    const int ce = ((t & 7) ^ (rt & 7)) << 3;         /* swizzled elem col */
    int gr = rt;
    if (PERM) gr = (rt & ~31) | ((rt & 15) << 1) | ((rt >> 4) & 1);
    g2l16(gbase + (long)(row0 + gr) * LDK + k0 + ce, lbuf + (l * 512 + t) * 8);
  }
}

#define FRAG_OFF(r, ks, hi) (((r) * 64 + (ks) * 32 + (hi) * 8) ^ (((r) & 7) << 3))

/* ---------------- FF GEMM: x = relu(A * B^T + b), de-interleave ------------ */
__global__ __launch_bounds__(512, 2)
void ff_gemm256(const u16* __restrict__ A, const u16* __restrict__ B,
                const float* __restrict__ bff,
                u16* __restrict__ sf, u16* __restrict__ ef) {
  __shared__ __align__(16) u16 lds[2][2][16384];    /* 128 KiB */
  const int tid = threadIdx.x, lane = tid & 63, wv = tid >> 6;
  const int wm = wv >> 2, wn = wv & 3;
  const int lr = lane & 15, hi = lane >> 4;

  const int bid = blockIdx.x;
  const int wg  = (bid & 7) * 96 + (bid >> 3);      /* XCD-chunked, bijective */
  const int tm  = wg & 15, tn = wg >> 4;            /* 16 x 48 tiles */
  const int rowA0 = tm * 256, rowB0 = tn * 256;

  f32x4 acc[8][4] = {};

  stage_tile<DDIM, false>(A, rowA0, 0, lds[0][0], tid);
  stage_tile<DDIM, true >(B, rowB0, 0, lds[0][1], tid);
  __syncthreads();

  int buf = 0;
  for (int t = 0; t < 16; ++t) {
    if (t < 15) {
      stage_tile<DDIM, false>(A, rowA0, (t + 1) * 64, lds[buf ^ 1][0], tid);
      stage_tile<DDIM, true >(B, rowB0, (t + 1) * 64, lds[buf ^ 1][1], tid);
    }
    const u16* La = lds[buf][0];
    const u16* Lb = lds[buf][1];
#pragma unroll
    for (int ks = 0; ks < 2; ++ks) {
      short8 af[8], bfr[4];
#pragma unroll
      for (int i = 0; i < 8; ++i) {
        const int r = wm * 128 + i * 16 + lr;
        af[i] = *reinterpret_cast<const short8*>(La + FRAG_OFF(r, ks, hi));
      }
#pragma unroll
      for (int j = 0; j < 4; ++j) {
        const int r = wn * 64 + j * 16 + lr;
        bfr[j] = *reinterpret_cast<const short8*>(Lb + FRAG_OFF(r, ks, hi));
      }
      __builtin_amdgcn_s_setprio(1);
#pragma unroll
      for (int i = 0; i < 8; ++i)
#pragma unroll
        for (int j = 0; j < 4; ++j)
          acc[i][j] = __builtin_amdgcn_mfma_f32_16x16x32_bf16(af[i], bfr[j], acc[i][j], 0, 0, 0);
      __builtin_amdgcn_s_setprio(0);
    }
    __syncthreads();
    buf ^= 1;
  }

  /* epilogue: +bias, relu, bf16; permuted cols -> contiguous-d stores */
#pragma unroll
  for (int j = 0; j < 4; ++j) {
    const int cblk = wn * 64 + j * 16;
    const int o = rowB0 + (cblk & ~31) + 2 * lr + ((cblk >> 4) & 1);
    const float bv = bff[o];
    const int label = o >> 9, d = (o >> 1) & 255, se = o & 1;
    u16* dst = se ? ef : sf;
#pragma unroll
    for (int i = 0; i < 8; ++i) {
#pragma unroll
      for (int r = 0; r < 4; ++r) {
        const int m = rowA0 + wm * 128 + i * 16 + hi * 4 + r;
        const int b = m >> 9, ll = m & 511;
        float v = acc[i][j][r] + bv;
        v = v > 0.f ? v : 0.f;
        dst[((long)(b * NLAB + label) * LSEQ + ll) * LDIM + d] = f2bf(v);
      }
    }
  }
}

/* ------------- Biaffine: per (b,label) S = sf * ef^T, dual write ----------- */
__global__ __launch_bounds__(512, 2)
void biaffine256(const u16* __restrict__ sf, const u16* __restrict__ ef,
                 const float* __restrict__ bias, const int* __restrict__ mask,
                 float* __restrict__ out) {
  __shared__ __align__(16) u16 lds[2][2][16384];    /* 128 KiB */
  const int tid = threadIdx.x, lane = tid & 63, wv = tid >> 6;
  const int wm = wv >> 2, wn = wv & 3;
  const int lr = lane & 15, hi = lane >> 4;

  const int bid = blockIdx.x;
  const int wg  = (bid & 7) * 96 + (bid >> 3);      /* 4 tiles of a bl share an XCD */
  const int bl  = wg >> 2, tile = wg & 3;
  const int tm  = tile >> 1, tn = tile & 1;
  const int b = bl / NLAB, label = bl - b * NLAB;
  const u16* Ab = sf + (long)bl * LSEQ * LDIM;
  const u16* Bb = ef + (long)bl * LSEQ * LDIM;
  const int rowA0 = tm * 256, rowB0 = tn * 256;

  f32x4 acc[8][4] = {};

  stage_tile<LDIM, false>(Ab, rowA0, 0, lds[0][0], tid);
  stage_tile<LDIM, false>(Bb, rowB0, 0, lds[0][1], tid);
  __syncthreads();

  int buf = 0;
  for (int t = 0; t < 4; ++t) {
    if (t < 3) {
      stage_tile<LDIM, false>(Ab, rowA0, (t + 1) * 64, lds[buf ^ 1][0], tid);
      stage_tile<LDIM, false>(Bb, rowB0, (t + 1) * 64, lds[buf ^ 1][1], tid);
    }
    const u16* La = lds[buf][0];
    const u16* Lb = lds[buf][1];
#pragma unroll
    for (int ks = 0; ks < 2; ++ks) {
      short8 af[8], bfr[4];
#pragma unroll
      for (int i = 0; i < 8; ++i) {
        const int r = wm * 128 + i * 16 + lr;
        af[i] = *reinterpret_cast<const short8*>(La + FRAG_OFF(r, ks, hi));
      }
#pragma unroll
      for (int j = 0; j < 4; ++j) {
        const int r = wn * 64 + j * 16 + lr;
        bfr[j] = *reinterpret_cast<const short8*>(Lb + FRAG_OFF(r, ks, hi));
      }
      __builtin_amdgcn_s_setprio(1);
#pragma unroll
      for (int i = 0; i < 8; ++i)
#pragma unroll
        for (int j = 0; j < 4; ++j)
          acc[i][j] = __builtin_amdgcn_mfma_f32_16x16x32_bf16(af[i], bfr[j], acc[i][j], 0, 0, 0);
      __builtin_amdgcn_s_setprio(0);
    }
    __syncthreads();
    buf ^= 1;
  }

  const float bv = bias[label];
  const long obase = (long)bl * LSEQ * LSEQ;
#pragma unroll
  for (int i = 0; i < 8; ++i) {
#pragma unroll
    for (int r = 0; r < 4; ++r) {
      const int s = rowA0 + wm * 128 + i * 16 + hi * 4 + r;
      const bool ms = (mask[b * LSEQ + s] != 0);
      const long rbase = obase + (long)s * LSEQ;
#pragma unroll
      for (int j = 0; j < 4; ++j) {
        const int e = rowB0 + wn * 64 + j * 16 + lr;
        float v = acc[i][j][r] + bv;
        u32 bits = __builtin_bit_cast(u32, v);
        if ((bits & 0x7F800000u) == 0x7F800000u) v = NEGV;  /* inf or nan */
        out[rbase + e] = v;
        const bool keep = (s <= e) && ms && (mask[b * LSEQ + e] != 0);
        out[MOFF + rbase + e] = keep ? v : NEGV;
      }
    }
  }
}

extern "C" void kernel_launch(void* const* d_in, const int* in_sizes, int n_in,
                              void* d_out, int out_size, void* d_ws, size_t ws_size,
                              hipStream_t stream) {
  const float* feat = (const float*)d_in[0];
  const int*   mask = (const int*)d_in[1];
  const float* wff  = (const float*)d_in[2];
  const float* bff  = (const float*)d_in[3];
  const float* bias = (const float*)d_in[4];
  float* out = (float*)d_out;

  u16* fA = (u16*)d_ws;                 /*  4,194,304 elems =  8 MiB  */
  u16* fB = fA + 4194304L;              /* 12,582,912 elems = 24 MiB  */
  u16* sf = fB + 12582912L;             /* 25,165,824 elems = 48 MiB  */
  u16* ef = sf + 25165824L;             /* 25,165,824 elems = 48 MiB  */

  cvt_bf16_kernel<<<2048, 256, 0, stream>>>(feat, wff, fA, fB);
  ff_gemm256<<<768, 512, 0, stream>>>(fA, fB, bff, sf, ef);
  biaffine256<<<768, 512, 0, stream>>>(sf, ef, bias, mask, out);
}